// Round 1
// baseline (465.117 us; speedup 1.0000x reference)
//
#include <hip/hip_runtime.h>
#include <math.h>

typedef __attribute__((ext_vector_type(8)))  short s16x8;   // 8 bf16 (4 VGPRs)
typedef __attribute__((ext_vector_type(16))) float f32x16;  // MFMA 32x32 acc

__device__ inline float bf_lo(unsigned u) { return __uint_as_float(u << 16); }
__device__ inline float bf_hi(unsigned u) { return __uint_as_float(u & 0xffff0000u); }
__device__ inline unsigned short f2bf(float f) {           // RNE f32 -> bf16
    unsigned u = __float_as_uint(f);
    u += 0x7fffu + ((u >> 16) & 1u);
    return (unsigned short)(u >> 16);
}
__device__ inline void acc_u4(float* a, uint4 v) {
    a[0] += bf_lo(v.x); a[1] += bf_hi(v.x);
    a[2] += bf_lo(v.y); a[3] += bf_hi(v.y);
    a[4] += bf_lo(v.z); a[5] += bf_hi(v.z);
    a[6] += bf_lo(v.w); a[7] += bf_hi(v.w);
}

#define BMAX 3200   // max edges per producer chunk (LDS-resident)
#define RNG  512    // owner ranges (= producer count); per-range nodes <= 256

// ===========================================================================
// Fused prep: x f32->bf16, 6 weight transposes, deg zeroing. One dispatch.
// ===========================================================================
__global__ __launch_bounds__(256)
void prep_fused(const float* __restrict__ x,   unsigned short* __restrict__ xbf,
                const float* __restrict__ W1a, unsigned short* __restrict__ W1aT,
                const float* __restrict__ W1b, unsigned short* __restrict__ W1bT,
                const float* __restrict__ W2a, unsigned short* __restrict__ W2aT,
                const float* __restrict__ W2b, unsigned short* __restrict__ W2bT,
                const float* __restrict__ W3a, unsigned short* __restrict__ W3aT,
                const float* __restrict__ W3b, unsigned short* __restrict__ W3bT,
                int* __restrict__ deg, int N) {
    int i = blockIdx.x * 256 + threadIdx.x;
    int nx = N * 48;
    if (i < nx) { xbf[i] = f2bf(x[i]); return; }
    i -= nx;
    if (i < N) { deg[i] = 0; return; }
    i -= N;
    if (i < 256 * 96)  { int n = i / 96,  k = i - n * 96;  W1aT[i] = f2bf(W1a[(size_t)k * 256 + n]); return; }
    i -= 256 * 96;
    if (i < 128 * 256) { int n = i / 256, k = i - n * 256; W1bT[i] = f2bf(W1b[(size_t)k * 128 + n]); return; }
    i -= 128 * 256;
    if (i < 256 * 304) { int n = i / 304, k = i - n * 304; W2aT[i] = f2bf(W2a[(size_t)k * 256 + n]); return; }
    i -= 256 * 304;
    if (i < 128 * 256) { int n = i / 256, k = i - n * 256; W2bT[i] = f2bf(W2b[(size_t)k * 128 + n]); return; }
    i -= 128 * 256;
    if (i < 256 * 304) { int n = i / 304, k = i - n * 304; W3aT[i] = f2bf(W3a[(size_t)k * 256 + n]); return; }
    i -= 256 * 304;
    if (i < 64 * 256)  { int n = i / 256, k = i - n * 256;
                         float v = (n < 40) ? W3b[(size_t)k * 40 + n] : 0.f;
                         W3bT[i] = f2bf(v); return; }
}

// ===========================================================================
// CSR build, fully atomic-free-global design (unchanged from prior rounds).
// ===========================================================================
__global__ __launch_bounds__(256)
void bucketize(const int* __restrict__ src, const int* __restrict__ dst,
               int2* __restrict__ pairs, int* __restrict__ offsg,
               int E, int C, int per) {
    __shared__ int sdst[BMAX];
    __shared__ int ssrc[BMAX];
    __shared__ int cnt[RNG];
    __shared__ int cur[RNG + 1];
    __shared__ int sh[256];
    const int p    = blockIdx.x;
    const int base = p * C;
    const int len  = min(C, E - base);
    const int t    = threadIdx.x;

    cnt[t] = 0; cnt[t + 256] = 0;
    for (int i = t; i < len; i += 256) { sdst[i] = dst[base + i]; ssrc[i] = src[base + i]; }
    __syncthreads();
    for (int i = t; i < len; i += 256) {
        int r = sdst[i] / per;
        atomicAdd(&cnt[r], 1);
    }
    __syncthreads();
    const int cA = cnt[2 * t], cB = cnt[2 * t + 1];
    sh[t] = cA + cB;
    __syncthreads();
    for (int off = 1; off < 256; off <<= 1) {
        int add = (t >= off) ? sh[t - off] : 0;
        __syncthreads();
        sh[t] += add;
        __syncthreads();
    }
    const int excl = sh[t] - cA - cB;
    cur[2 * t] = excl;
    cur[2 * t + 1] = excl + cA;
    if (t == 255) cur[RNG] = sh[255];
    offsg[p * (RNG + 1) + 2 * t]     = excl;
    offsg[p * (RNG + 1) + 2 * t + 1] = excl + cA;
    if (t == 255) offsg[p * (RNG + 1) + RNG] = sh[255];
    __syncthreads();
    for (int i = t; i < len; i += 256) {
        int d = sdst[i];
        int r = d / per;
        int pos = atomicAdd(&cur[r], 1);
        pairs[base + pos] = make_int2(ssrc[i], d);
    }
}

__global__ __launch_bounds__(256)
void deg_owned(const int2* __restrict__ pairs, const int* __restrict__ offsg,
               int* __restrict__ deg, int N, int C, int per) {
    __shared__ int po[RNG];
    __shared__ int W[RNG + 1];
    __shared__ int sh[256];
    __shared__ int dcnt[256];
    const int r  = blockIdx.x;
    const int lo = r * per;
    const int hi = min(lo + per, N);
    const int cnt = hi - lo;
    if (cnt <= 0) return;
    const int t = threadIdx.x;
    if (t < cnt) dcnt[t] = 0;
    const int pA = 2 * t, pB = 2 * t + 1;
    const int oA0 = offsg[pA * (RNG + 1) + r];
    const int oA1 = offsg[pA * (RNG + 1) + r + 1];
    const int oB0 = offsg[pB * (RNG + 1) + r];
    const int oB1 = offsg[pB * (RNG + 1) + r + 1];
    po[pA] = oA0; po[pB] = oB0;
    const int cA = oA1 - oA0, cB = oB1 - oB0;
    sh[t] = cA + cB;
    __syncthreads();
    for (int off = 1; off < 256; off <<= 1) {
        int add = (t >= off) ? sh[t - off] : 0;
        __syncthreads();
        sh[t] += add;
        __syncthreads();
    }
    const int excl = sh[t] - cA - cB;
    W[pA] = excl; W[pB] = excl + cA;
    if (t == 255) W[RNG] = sh[255];
    __syncthreads();
    const int tot = W[RNG];
    for (int i = t; i < tot; i += 256) {
        int a = 0, b = RNG;
        while (b - a > 1) { int m = (a + b) >> 1; if (W[m] <= i) a = m; else b = m; }
        const int2 pr = pairs[(size_t)a * C + po[a] + (i - W[a])];
        atomicAdd(&dcnt[pr.y - lo], 1);
    }
    __syncthreads();
    if (t < cnt) deg[lo + t] = dcnt[t];
}

__global__ __launch_bounds__(256)
void place_owned(const int2* __restrict__ pairs, const int* __restrict__ offsg,
                 const int* __restrict__ rowptr, int* __restrict__ csr_src,
                 int N, int C, int per, int E) {
    __shared__ int po[RNG];
    __shared__ int W[RNG + 1];
    __shared__ int sh[256];
    __shared__ int curs[256];
    const int r  = blockIdx.x;
    const int lo = r * per;
    const int hi = min(lo + per, N);
    const int cnt = hi - lo;
    if (cnt <= 0) return;
    const int t = threadIdx.x;
    if (t < cnt) curs[t] = rowptr[lo + t];   // fresh every launch: replay-safe
    const int pA = 2 * t, pB = 2 * t + 1;
    const int oA0 = offsg[pA * (RNG + 1) + r];
    const int oA1 = offsg[pA * (RNG + 1) + r + 1];
    const int oB0 = offsg[pB * (RNG + 1) + r];
    const int oB1 = offsg[pB * (RNG + 1) + r + 1];
    po[pA] = oA0; po[pB] = oB0;
    const int cA = oA1 - oA0, cB = oB1 - oB0;
    sh[t] = cA + cB;
    __syncthreads();
    for (int off = 1; off < 256; off <<= 1) {
        int add = (t >= off) ? sh[t - off] : 0;
        __syncthreads();
        sh[t] += add;
        __syncthreads();
    }
    const int excl = sh[t] - cA - cB;
    W[pA] = excl; W[pB] = excl + cA;
    if (t == 255) W[RNG] = sh[255];
    __syncthreads();
    const int tot = W[RNG];
    for (int i = t; i < tot; i += 256) {
        int a = 0, b = RNG;
        while (b - a > 1) { int m = (a + b) >> 1; if (W[m] <= i) a = m; else b = m; }
        const int2 pr = pairs[(size_t)a * C + po[a] + (i - W[a])];
        const int pos = atomicAdd(&curs[pr.y - lo], 1);   // LDS atomic
        if (pos < E) csr_src[pos] = pr.x;
    }
}

__global__ __launch_bounds__(256)
void scan_block_sums(const int* __restrict__ deg, int* __restrict__ bsum, int N) {
    __shared__ int sh[256];
    int base = blockIdx.x * 1024 + threadIdx.x * 4;
    int s = 0;
    #pragma unroll
    for (int k = 0; k < 4; ++k) { int i = base + k; if (i < N) s += deg[i]; }
    sh[threadIdx.x] = s;
    __syncthreads();
    for (int off = 128; off >= 1; off >>= 1) {
        if (threadIdx.x < off) sh[threadIdx.x] += sh[threadIdx.x + off];
        __syncthreads();
    }
    if (threadIdx.x == 0) bsum[blockIdx.x] = sh[0];
}

__global__ __launch_bounds__(256)
void scan_bsums(int* __restrict__ bsum, int nb) {
    __shared__ int sh[256];
    int t = threadIdx.x;
    int v = (t < nb) ? bsum[t] : 0;
    sh[t] = v;
    __syncthreads();
    for (int off = 1; off < 256; off <<= 1) {
        int add = (t >= off) ? sh[t - off] : 0;
        __syncthreads();
        sh[t] += add;
        __syncthreads();
    }
    if (t < nb) bsum[t] = sh[t] - v;
}

__global__ __launch_bounds__(256)
void scan_finalize(const int* __restrict__ deg, const int* __restrict__ bsum,
                   int* __restrict__ rowptr, int N) {
    __shared__ int sh[256];
    int t = threadIdx.x;
    int base = blockIdx.x * 1024 + t * 4;
    int loc[4];
    int s = 0;
    #pragma unroll
    for (int k = 0; k < 4; ++k) {
        int i = base + k;
        loc[k] = (i < N) ? deg[i] : 0;
        s += loc[k];
    }
    sh[t] = s;
    __syncthreads();
    for (int off = 1; off < 256; off <<= 1) {
        int add = (t >= off) ? sh[t - off] : 0;
        __syncthreads();
        sh[t] += add;
        __syncthreads();
    }
    int run = bsum[blockIdx.x] + sh[t] - s;
    #pragma unroll
    for (int k = 0; k < 4; ++k) {
        int i = base + k;
        if (i < N) rowptr[i] = run;
        run += loc[k];
    }
}

// ===========================================================================
// Fused LGConv-gather + 2-layer MLP, bf16 MFMA (32x32x16), 64 rows/block.
// Round-13 change: the gather (previously a separate lgconv dispatch writing
// c1/c2 to HBM) now fills the A-tile's first LA columns directly in LDS.
// Each block gathers its own 64 rows' edges (f32 accumulate, bf16 pack);
// gather-latency of block k overlaps MFMA of block j via 4 blocks/CU.
// ===========================================================================
template<int LA, int LB, int LC, bool LSM>
__global__ __launch_bounds__(256)
void fused_gconv_mlp(const unsigned short* __restrict__ gsrc,   // table gathered via CSR
                     const unsigned short* __restrict__ segB,
                     const unsigned short* __restrict__ segC,
                     const int* __restrict__ rowptr,
                     const int* __restrict__ deg,
                     const int* __restrict__ csr_src,
                     const unsigned short* __restrict__ WaT, const float* __restrict__ ba,
                     const unsigned short* __restrict__ WbT, const float* __restrict__ bb,
                     void* __restrict__ outv, int n) {
    constexpr int K1   = LA + LB + LC;      // 96 or 304
    constexpr int NS1  = K1 / 16;
    constexpr int KPAD = K1 + 8;            // 104 or 312 (16B-aligned rows)
    constexpr int K2P  = 264;               // hid row stride (bf16)
    constexpr int SW   = (64 * KPAD > 64 * K2P) ? 64 * KPAD : 64 * K2P;
    __shared__ __attribute__((aligned(16))) unsigned short smem[SW];
    unsigned short* Ab  = smem;             // stage-1 A tile   [64][KPAD]
    unsigned short* hid = smem;             // stage-1 out      [64][K2P] (union)

    const int tid  = threadIdx.x;
    const int wave = tid >> 6;
    const int lane = tid & 63;
    const int l31  = lane & 31;
    const int lh   = lane >> 5;
    const int row0 = blockIdx.x * 64;

    // ---- gather phase: 4 threads/node, f32 accumulate, bf16 pack into Ab ----
    {
        constexpr int NCHA = LA / 8;                 // 16B chunks of gathered seg
        constexpr int MAXC = (NCHA + 3) / 4;         // chunks per thread (2 or 4)
        constexpr bool FULL = (NCHA % 4 == 0);
        const int gm  = tid >> 2;                    // node slot 0..63
        const int gj  = tid & 3;
        const int row = row0 + gm;
        float acc[MAXC][8];
        #pragma unroll
        for (int ci = 0; ci < MAXC; ++ci)
            #pragma unroll
            for (int k = 0; k < 8; ++k) acc[ci][k] = 0.f;
        if (row < n) {
            const int start = rowptr[row];
            const int dg    = deg[row];
            int e = 0;
            for (; e + 1 < dg; e += 2) {
                const int s0 = csr_src[start + e];
                const int s1 = csr_src[start + e + 1];
                const unsigned short* xp0 = gsrc + (size_t)s0 * LA;
                const unsigned short* xp1 = gsrc + (size_t)s1 * LA;
                #pragma unroll
                for (int ci = 0; ci < MAXC; ++ci) {
                    const int ch8 = (gj + 4 * ci) * 8;
                    if (FULL || ch8 < LA) {
                        uint4 v0 = *(const uint4*)(xp0 + ch8);
                        uint4 v1 = *(const uint4*)(xp1 + ch8);
                        acc_u4(acc[ci], v0);
                        acc_u4(acc[ci], v1);
                    }
                }
            }
            if (e < dg) {
                const int s0 = csr_src[start + e];
                const unsigned short* xp0 = gsrc + (size_t)s0 * LA;
                #pragma unroll
                for (int ci = 0; ci < MAXC; ++ci) {
                    const int ch8 = (gj + 4 * ci) * 8;
                    if (FULL || ch8 < LA) {
                        uint4 v0 = *(const uint4*)(xp0 + ch8);
                        acc_u4(acc[ci], v0);
                    }
                }
            }
        }
        #pragma unroll
        for (int ci = 0; ci < MAXC; ++ci) {
            const int ch8 = (gj + 4 * ci) * 8;
            if (FULL || ch8 < LA) {
                uint4 o;
                o.x = ((unsigned)f2bf(acc[ci][1]) << 16) | f2bf(acc[ci][0]);
                o.y = ((unsigned)f2bf(acc[ci][3]) << 16) | f2bf(acc[ci][2]);
                o.z = ((unsigned)f2bf(acc[ci][5]) << 16) | f2bf(acc[ci][4]);
                o.w = ((unsigned)f2bf(acc[ci][7]) << 16) | f2bf(acc[ci][6]);
                *(uint4*)(Ab + gm * KPAD + ch8) = o;
            }
        }
    }

    // ---- stage B/C segments: coalesced uint4 ----
    {
        constexpr int NCHBC = (LB + LC) / 8;
        for (int c = tid; c < 64 * NCHBC; c += 256) {
            const int m  = c / NCHBC;
            const int kc = c - m * NCHBC;
            const int row = row0 + m;
            const int ra  = (row < n) ? row : (n - 1);
            const unsigned short* sp;
            int koff;
            if (kc * 8 < LB) { sp = segB + (size_t)ra * LB; koff = kc * 8; }
            else             { sp = segC + (size_t)ra * LC; koff = kc * 8 - LB; }
            *(uint4*)(Ab + m * KPAD + LA + kc * 8) = *(const uint4*)(sp + koff);
        }
    }
    __syncthreads();

    // ---------------- stage 1 ----------------
    f32x16 acc00 = {}, acc01 = {}, acc10 = {}, acc11 = {};
    const unsigned short* wa0 = WaT + (size_t)(wave * 64 + l31) * K1 + lh * 8;
    const unsigned short* wa1 = wa0 + (size_t)32 * K1;
    const int a0off = l31 * KPAD + lh * 8;
    const int a1off = (l31 + 32) * KPAD + lh * 8;

    #pragma unroll
    for (int s = 0; s < NS1; ++s) {
        const int k0 = s * 16;
        s16x8 a0 = *(const s16x8*)(Ab + a0off + k0);
        s16x8 a1 = *(const s16x8*)(Ab + a1off + k0);
        s16x8 b0 = *(const s16x8*)(wa0 + k0);
        s16x8 b1 = *(const s16x8*)(wa1 + k0);
        acc00 = __builtin_amdgcn_mfma_f32_32x32x16_bf16(a0, b0, acc00, 0, 0, 0);
        acc01 = __builtin_amdgcn_mfma_f32_32x32x16_bf16(a0, b1, acc01, 0, 0, 0);
        acc10 = __builtin_amdgcn_mfma_f32_32x32x16_bf16(a1, b0, acc10, 0, 0, 0);
        acc11 = __builtin_amdgcn_mfma_f32_32x32x16_bf16(a1, b1, acc11, 0, 0, 0);
    }
    __syncthreads();                        // all A reads done before hid overwrites

    // epilogue: + bias, relu -> hid[m][k] bf16 (C/D layout, m74/m101)
    {
        const int c0 = wave * 64 + l31;
        const int c1 = c0 + 32;
        const float bias0 = ba[c0];
        const float bias1 = ba[c1];
        #pragma unroll
        for (int t = 0; t < 16; ++t) {
            int rloc = (t & 3) + 8 * (t >> 2) + 4 * lh;
            hid[rloc * K2P + c0]        = f2bf(fmaxf(acc00[t] + bias0, 0.f));
            hid[rloc * K2P + c1]        = f2bf(fmaxf(acc01[t] + bias1, 0.f));
            hid[(rloc + 32) * K2P + c0] = f2bf(fmaxf(acc10[t] + bias0, 0.f));
            hid[(rloc + 32) * K2P + c1] = f2bf(fmaxf(acc11[t] + bias1, 0.f));
        }
    }
    __syncthreads();

    // ---------------- stage 2 ----------------
    if (!LSM) {
        f32x16 d0 = {}, d1 = {};
        const unsigned short* wb = WbT + (size_t)(wave * 32 + l31) * 256 + lh * 8;
        const int h0 = l31 * K2P + lh * 8;
        #pragma unroll
        for (int s = 0; s < 16; ++s) {
            s16x8 a0 = *(const s16x8*)&hid[h0 + s * 16];
            s16x8 a1 = *(const s16x8*)&hid[h0 + 32 * K2P + s * 16];
            s16x8 b  = *(const s16x8*)(wb + s * 16);
            d0 = __builtin_amdgcn_mfma_f32_32x32x16_bf16(a0, b, d0, 0, 0, 0);
            d1 = __builtin_amdgcn_mfma_f32_32x32x16_bf16(a1, b, d1, 0, 0, 0);
        }
        const int col = wave * 32 + l31;
        const float bias = bb[col];
        unsigned short* out = (unsigned short*)outv;
        #pragma unroll
        for (int t = 0; t < 16; ++t) {
            int rloc = (t & 3) + 8 * (t >> 2) + 4 * lh;
            int rr0 = row0 + rloc, rr1 = rr0 + 32;
            if (rr0 < n) out[(size_t)rr0 * 128 + col] = f2bf(fmaxf(d0[t] + bias, 0.f));
            if (rr1 < n) out[(size_t)rr1 * 128 + col] = f2bf(fmaxf(d1[t] + bias, 0.f));
        }
    } else {
        const int rt = wave & 1, ct = wave >> 1;
        f32x16 d = {};
        const unsigned short* wb = WbT + (size_t)(ct * 32 + l31) * 256 + lh * 8;
        const int h0 = (rt * 32 + l31) * K2P + lh * 8;
        #pragma unroll
        for (int s = 0; s < 16; ++s) {
            s16x8 a = *(const s16x8*)&hid[h0 + s * 16];
            s16x8 b = *(const s16x8*)(wb + s * 16);
            d = __builtin_amdgcn_mfma_f32_32x32x16_bf16(a, b, d, 0, 0, 0);
        }
        __syncthreads();                    // done reading hid; reuse as logits
        float* lg = (float*)smem;           // [64][68] f32 = 17.4KB
        const int col = ct * 32 + l31;
        const float bias = (col < 40) ? bb[col] : 0.f;
        #pragma unroll
        for (int t = 0; t < 16; ++t) {
            int rloc = rt * 32 + (t & 3) + 8 * (t >> 2) + 4 * lh;
            lg[rloc * 68 + col] = d[t] + bias;
        }
        __syncthreads();
        const int r = tid >> 2, j = tid & 3;
        float mx = -1e30f;
        #pragma unroll
        for (int c = 0; c < 10; ++c) mx = fmaxf(mx, lg[r * 68 + j * 10 + c]);
        mx = fmaxf(mx, __shfl_xor(mx, 1));
        mx = fmaxf(mx, __shfl_xor(mx, 2));
        float sm = 0.f;
        #pragma unroll
        for (int c = 0; c < 10; ++c) sm += __expf(lg[r * 68 + j * 10 + c] - mx);
        sm += __shfl_xor(sm, 1);
        sm += __shfl_xor(sm, 2);
        const float lse = mx + __logf(sm);
        const int row = row0 + r;
        float* out = (float*)outv;
        if (row < n) {
            #pragma unroll
            for (int c = 0; c < 10; ++c)
                out[(size_t)row * 40 + j * 10 + c] = lg[r * 68 + j * 10 + c] - lse;
        }
    }
}

// ===========================================================================
extern "C" void kernel_launch(void* const* d_in, const int* in_sizes, int n_in,
                              void* d_out, int out_size, void* d_ws, size_t ws_size,
                              hipStream_t stream) {
    const float* x   = (const float*)d_in[0];
    const int*   ei  = (const int*)d_in[1];
    const float* W1a = (const float*)d_in[2];
    const float* b1a = (const float*)d_in[3];
    const float* W1b = (const float*)d_in[4];
    const float* b1b = (const float*)d_in[5];
    const float* W2a = (const float*)d_in[6];
    const float* b2a = (const float*)d_in[7];
    const float* W2b = (const float*)d_in[8];
    const float* b2b = (const float*)d_in[9];
    const float* W3a = (const float*)d_in[10];
    const float* b3a = (const float*)d_in[11];
    const float* W3b = (const float*)d_in[12];
    const float* b3b = (const float*)d_in[13];
    float* out = (float*)d_out;

    const int E = in_sizes[1] / 2;
    const int N = in_sizes[0] / 48;
    const int* src = ei;
    const int* dst = ei + E;

    const int nprod = RNG;                      // 512 producers == 512 owners
    const int C     = (E + nprod - 1) / nprod;  // 3125 for E=1.6M (<= BMAX)
    const int per   = (N + RNG - 1) / RNG;      // 196 nodes/owner (<= 256)

    // ---- workspace carve-up (256B aligned) ----
    char* p = (char*)d_ws;
    auto alloc = [&](size_t bytes) { void* q = p; p += (bytes + 255) & ~(size_t)255; return q; };
    unsigned short* xbf  = (unsigned short*)alloc((size_t)N * 48  * 2);
    unsigned short* h1   = (unsigned short*)alloc((size_t)N * 128 * 2);
    unsigned short* h2   = (unsigned short*)alloc((size_t)N * 128 * 2);
    unsigned short* W1aT = (unsigned short*)alloc((size_t)256 * 96  * 2);
    unsigned short* W1bT = (unsigned short*)alloc((size_t)128 * 256 * 2);
    unsigned short* W2aT = (unsigned short*)alloc((size_t)256 * 304 * 2);
    unsigned short* W2bT = (unsigned short*)alloc((size_t)128 * 256 * 2);
    unsigned short* W3aT = (unsigned short*)alloc((size_t)256 * 304 * 2);
    unsigned short* W3bT = (unsigned short*)alloc((size_t)64  * 256 * 2);
    int* deg     = (int*)alloc((size_t)N * 4);
    int* rowptr  = (int*)alloc((size_t)N * 4);
    int* bsum    = (int*)alloc(1024);
    int* csr_src = (int*)alloc((size_t)E * 4);
    int2* pairs  = (int2*)alloc((size_t)nprod * C * 8);
    int* offsg   = (int*)alloc((size_t)nprod * (RNG + 1) * 4);

    const int nb_scan = (N + 1023) / 1024;
    const int nblk    = (N + 63) / 64;

    // ---- fused prep (x->bf16, 6 transposes, deg=0) ----
    {
        int total = N * 48 + N + 256*96 + 128*256 + 256*304 + 128*256 + 256*304 + 64*256;
        prep_fused<<<(total + 255) / 256, 256, 0, stream>>>(
            x, xbf, W1a, W1aT, W1b, W1bT, W2a, W2aT, W2b, W2bT,
            W3a, W3aT, W3b, W3bT, deg, N);
    }

    // ---- CSR build (bucketize -> owned deg -> scan -> owned place) ----
    bucketize<<<nprod, 256, 0, stream>>>(src, dst, pairs, offsg, E, C, per);
    deg_owned<<<RNG, 256, 0, stream>>>(pairs, offsg, deg, N, C, per);
    scan_block_sums<<<nb_scan, 256, 0, stream>>>(deg, bsum, N);
    scan_bsums<<<1, 256, 0, stream>>>(bsum, nb_scan);
    scan_finalize<<<nb_scan, 256, 0, stream>>>(deg, bsum, rowptr, N);
    place_owned<<<RNG, 256, 0, stream>>>(pairs, offsg, rowptr, csr_src, N, C, per, E);

    // ---- layer 1 (fused gather + MLP) ----
    fused_gconv_mlp<48, 48, 0, false><<<nblk, 256, 0, stream>>>(
        xbf, xbf, (const unsigned short*)nullptr, rowptr, deg, csr_src,
        W1aT, b1a, W1bT, b1b, h1, N);

    // ---- layer 2 ----
    fused_gconv_mlp<128, 128, 48, false><<<nblk, 256, 0, stream>>>(
        h1, h1, xbf, rowptr, deg, csr_src,
        W2aT, b2a, W2bT, b2b, h2, N);

    // ---- layer 3 ----
    fused_gconv_mlp<128, 128, 48, true><<<nblk, 256, 0, stream>>>(
        h2, h2, xbf, rowptr, deg, csr_src,
        W3aT, b3a, W3bT, b3b, out, N);
}